// Round 4
// baseline (58.354 us; speedup 1.0000x reference)
//
#include <hip/hip_runtime.h>

#define H_DIM 1024
#define W_DIM 1024
#define EPS 1e-6f
#define R_ROWS 8
#define N_LOAD (R_ROWS + 4)   // rows h0-2 .. h0+R_ROWS+1

typedef float vfloat4 __attribute__((ext_vector_type(4)));

// x_v[h,w] = -10*x[h-2,w] - x[h-1,w] + x[h+1,w] + 10*x[h+2,w]   (zero pad)
// x_h[h,w] = -10*x[h,w-2] - x[h,w-1] + x[h,w+1] + 10*x[h,w+2]   (zero pad)
// out = sqrt(x_v^2 + x_h^2 + EPS)
//
// Each thread: 4 contiguous columns (float4) x R_ROWS rows. ALL 12 input
// rows are loaded up front (independent back-to-back global_load_dwordx4)
// so HBM/L3 latency is hidden by MLP instead of being exposed per-row.
// Horizontal neighbors via intra-wave __shfl; lanes 0/63 do predicated
// scalar patch-up loads.

__global__ __launch_bounds__(256) void grad_mag_kernel(
    const float* __restrict__ x, float* __restrict__ out) {
    const int tid  = threadIdx.x;
    const int lane = tid & 63;
    const int w0   = tid * 4;                 // 256 threads * 4 = 1024 = full row
    const int h0   = blockIdx.y * R_ROWS;
    const size_t planeOff = (size_t)blockIdx.z * (size_t)(H_DIM * W_DIM);
    const float* __restrict__ xp = x + planeOff;
    float*       __restrict__ op = out + planeOff;

    float4 win[N_LOAD];

    const bool interior = (h0 >= 2) && (h0 + R_ROWS + 1 < H_DIM);
    if (interior) {
        // fast path: 12 unconditional loads, all issued before any use
        #pragma unroll
        for (int r = 0; r < N_LOAD; ++r) {
            win[r] = *reinterpret_cast<const float4*>(
                xp + (size_t)(h0 - 2 + r) * W_DIM + w0);
        }
    } else {
        #pragma unroll
        for (int r = 0; r < N_LOAD; ++r) {
            const int h = h0 - 2 + r;
            if (h >= 0 && h < H_DIM) {
                win[r] = *reinterpret_cast<const float4*>(
                    xp + (size_t)h * W_DIM + w0);
            } else {
                win[r] = make_float4(0.f, 0.f, 0.f, 0.f);
            }
        }
    }

    #pragma unroll
    for (int i = 0; i < R_ROWS; ++i) {
        const float4 m2 = win[i + 0];
        const float4 m1 = win[i + 1];
        const float4 c  = win[i + 2];
        const float4 p1 = win[i + 3];
        const float4 p2 = win[i + 4];

        // horizontal neighbors from adjacent lanes
        float wl2 = __shfl_up(c.z, 1);    // row[w0-2]
        float wl1 = __shfl_up(c.w, 1);    // row[w0-1]
        float wr4 = __shfl_down(c.x, 1);  // row[w0+4]
        float wr5 = __shfl_down(c.y, 1);  // row[w0+5]
        if (lane == 0) {
            const float* row = xp + (size_t)(h0 + i) * W_DIM;
            wl2 = (w0 >= 2) ? row[w0 - 2] : 0.f;
            wl1 = (w0 >= 1) ? row[w0 - 1] : 0.f;
        }
        if (lane == 63) {
            const float* row = xp + (size_t)(h0 + i) * W_DIM;
            wr4 = (w0 + 4 < W_DIM) ? row[w0 + 4] : 0.f;
            wr5 = (w0 + 5 < W_DIM) ? row[w0 + 5] : 0.f;
        }

        float4 xv;
        xv.x = -10.f * m2.x - m1.x + p1.x + 10.f * p2.x;
        xv.y = -10.f * m2.y - m1.y + p1.y + 10.f * p2.y;
        xv.z = -10.f * m2.z - m1.z + p1.z + 10.f * p2.z;
        xv.w = -10.f * m2.w - m1.w + p1.w + 10.f * p2.w;

        float4 xh;
        xh.x = -10.f * wl2 - wl1 + c.y + 10.f * c.z;
        xh.y = -10.f * wl1 - c.x + c.z + 10.f * c.w;
        xh.z = -10.f * c.x - c.y + c.w + 10.f * wr4;
        xh.w = -10.f * c.y - c.z + wr4 + 10.f * wr5;

        vfloat4 o;
        o.x = sqrtf(xv.x * xv.x + xh.x * xh.x + EPS);
        o.y = sqrtf(xv.y * xv.y + xh.y * xh.y + EPS);
        o.z = sqrtf(xv.z * xv.z + xh.z * xh.z + EPS);
        o.w = sqrtf(xv.w * xv.w + xh.w * xh.w + EPS);

        // nontemporal: output is write-once; don't evict L3-resident input
        __builtin_nontemporal_store(
            o, reinterpret_cast<vfloat4*>(op + (size_t)(h0 + i) * W_DIM + w0));
    }
}

extern "C" void kernel_launch(void* const* d_in, const int* in_sizes, int n_in,
                              void* d_out, int out_size, void* d_ws, size_t ws_size,
                              hipStream_t stream) {
    const float* x   = (const float*)d_in[0];
    float*       out = (float*)d_out;
    const int planes = in_sizes[0] / (H_DIM * W_DIM);  // 16*2 = 32

    dim3 block(256, 1, 1);
    dim3 grid(1, H_DIM / R_ROWS, planes);  // (1, 128, 32)
    grad_mag_kernel<<<grid, block, 0, stream>>>(x, out);
}

// Round 5
// 49.763 us; speedup vs baseline: 1.1726x; 1.1726x over previous
//
#include <hip/hip_runtime.h>

#define H_DIM 1024
#define W_DIM 1024
#define EPS 1e-6f
#define R_ROWS 16
#define NXCD 8

typedef float vfloat4 __attribute__((ext_vector_type(4)));

// x_v[h,w] = -10*x[h-2,w] - x[h-1,w] + x[h+1,w] + 10*x[h+2,w]   (zero pad)
// x_h[h,w] = -10*x[h,w-2] - x[h,w-1] + x[h,w+1] + 10*x[h,w+2]   (zero pad)
// out = sqrt(x_v^2 + x_h^2 + EPS)
//
// R1 structure (best measured): 16 output rows/thread, 5-row register
// sliding window, fully unrolled. Horizontal neighbors via intra-wave
// __shfl; lanes 0/63 do predicated scalar patch-up loads. NT stores.
// NEW: bijective chunked XCD swizzle — each XCD gets a contiguous chunk
// of 256 blocks (= 8 whole planes, h-blocks in order), so halo rows are
// shared within one XCD's L2 and the HBM stream per XCD is sequential.

__global__ __launch_bounds__(256) void grad_mag_kernel(
    const float* __restrict__ x, float* __restrict__ out) {
    // ---- XCD-aware block swizzle (nwg = 2048, 2048 % 8 == 0) ----
    const int bid = blockIdx.x;
    const int nb  = (bid & (NXCD - 1)) * (2048 / NXCD) + (bid >> 3);
    const int plane = nb >> 6;        // nb / 64
    const int hb    = nb & 63;        // nb % 64
    const int h0    = hb * R_ROWS;

    const int tid  = threadIdx.x;
    const int lane = tid & 63;
    const int w0   = tid * 4;         // 256 threads * 4 = 1024 = full row
    const size_t planeOff = (size_t)plane * (size_t)(H_DIM * W_DIM);
    const float* __restrict__ xp = x + planeOff;
    float*       __restrict__ op = out + planeOff;

    float4 win[5];

    auto loadRow = [&](int h, float4& v) {
        if (h >= 0 && h < H_DIM) {
            v = *reinterpret_cast<const float4*>(xp + (size_t)h * W_DIM + w0);
        } else {
            v = make_float4(0.f, 0.f, 0.f, 0.f);
        }
    };

    // Preload rows h0-2 .. h0+1 into window slots 0..3
    loadRow(h0 - 2, win[0]);
    loadRow(h0 - 1, win[1]);
    loadRow(h0 + 0, win[2]);
    loadRow(h0 + 1, win[3]);

    #pragma unroll
    for (int i = 0; i < R_ROWS; ++i) {
        // bring in row h0+i+2 (the "+2" tap for output row h0+i)
        loadRow(h0 + i + 2, win[(i + 4) % 5]);

        const float4 m2 = win[(i + 0) % 5];
        const float4 m1 = win[(i + 1) % 5];
        const float4 c  = win[(i + 2) % 5];
        const float4 p1 = win[(i + 3) % 5];
        const float4 p2 = win[(i + 4) % 5];

        // horizontal neighbors from adjacent lanes
        float wl2 = __shfl_up(c.z, 1);    // row[w0-2]
        float wl1 = __shfl_up(c.w, 1);    // row[w0-1]
        float wr4 = __shfl_down(c.x, 1);  // row[w0+4]
        float wr5 = __shfl_down(c.y, 1);  // row[w0+5]
        if (lane == 0) {
            const float* row = xp + (size_t)(h0 + i) * W_DIM;
            wl2 = (w0 >= 2) ? row[w0 - 2] : 0.f;
            wl1 = (w0 >= 1) ? row[w0 - 1] : 0.f;
        }
        if (lane == 63) {
            const float* row = xp + (size_t)(h0 + i) * W_DIM;
            wr4 = (w0 + 4 < W_DIM) ? row[w0 + 4] : 0.f;
            wr5 = (w0 + 5 < W_DIM) ? row[w0 + 5] : 0.f;
        }

        float4 xv;
        xv.x = -10.f * m2.x - m1.x + p1.x + 10.f * p2.x;
        xv.y = -10.f * m2.y - m1.y + p1.y + 10.f * p2.y;
        xv.z = -10.f * m2.z - m1.z + p1.z + 10.f * p2.z;
        xv.w = -10.f * m2.w - m1.w + p1.w + 10.f * p2.w;

        float4 xh;
        xh.x = -10.f * wl2 - wl1 + c.y + 10.f * c.z;
        xh.y = -10.f * wl1 - c.x + c.z + 10.f * c.w;
        xh.z = -10.f * c.x - c.y + c.w + 10.f * wr4;
        xh.w = -10.f * c.y - c.z + wr4 + 10.f * wr5;

        vfloat4 o;
        o.x = sqrtf(xv.x * xv.x + xh.x * xh.x + EPS);
        o.y = sqrtf(xv.y * xv.y + xh.y * xh.y + EPS);
        o.z = sqrtf(xv.z * xv.z + xh.z * xh.z + EPS);
        o.w = sqrtf(xv.w * xv.w + xh.w * xh.w + EPS);

        // nontemporal: output is write-once; don't evict L3-resident input
        __builtin_nontemporal_store(
            o, reinterpret_cast<vfloat4*>(op + (size_t)(h0 + i) * W_DIM + w0));
    }
}

extern "C" void kernel_launch(void* const* d_in, const int* in_sizes, int n_in,
                              void* d_out, int out_size, void* d_ws, size_t ws_size,
                              hipStream_t stream) {
    const float* x   = (const float*)d_in[0];
    float*       out = (float*)d_out;
    const int planes = in_sizes[0] / (H_DIM * W_DIM);  // 16*2 = 32
    const int nwg = planes * (H_DIM / R_ROWS);         // 32 * 64 = 2048

    dim3 block(256, 1, 1);
    dim3 grid(nwg, 1, 1);
    grad_mag_kernel<<<grid, block, 0, stream>>>(x, out);
}

// Round 6
// 47.237 us; speedup vs baseline: 1.2353x; 1.0535x over previous
//
#include <hip/hip_runtime.h>

#define H_DIM 1024
#define W_DIM 1024
#define EPS 1e-6f
#define R_ROWS 32
#define NXCD 8

typedef float vfloat4 __attribute__((ext_vector_type(4)));

// x_v[h,w] = -10*x[h-2,w] - x[h-1,w] + x[h+1,w] + 10*x[h+2,w]   (zero pad)
// x_h[h,w] = -10*x[h,w-2] - x[h,w-1] + x[h,w+1] + 10*x[h,w+2]   (zero pad)
// out = sqrt(x_v^2 + x_h^2 + EPS)
//
// 32 output rows/thread, 5-row register sliding window, fully unrolled.
// Horizontal neighbors via intra-wave __shfl; lanes 0/63 do predicated
// scalar patch-up loads. NT stores. Bijective chunked XCD swizzle so each
// XCD walks contiguous h-blocks of its own planes (halo reuse in own L2).

__global__ __launch_bounds__(256) void grad_mag_kernel(
    const float* __restrict__ x, float* __restrict__ out) {
    // ---- XCD-aware block swizzle (nwg = 1024, 1024 % 8 == 0) ----
    const int bid = blockIdx.x;
    const int nb  = (bid & (NXCD - 1)) * (1024 / NXCD) + (bid >> 3);
    const int plane = nb >> 5;        // nb / 32   (32 h-blocks per plane)
    const int hb    = nb & 31;        // nb % 32
    const int h0    = hb * R_ROWS;

    const int tid  = threadIdx.x;
    const int lane = tid & 63;
    const int w0   = tid * 4;         // 256 threads * 4 = 1024 = full row
    const size_t planeOff = (size_t)plane * (size_t)(H_DIM * W_DIM);
    const float* __restrict__ xp = x + planeOff;
    float*       __restrict__ op = out + planeOff;

    float4 win[5];

    auto loadRow = [&](int h, float4& v) {
        if (h >= 0 && h < H_DIM) {
            v = *reinterpret_cast<const float4*>(xp + (size_t)h * W_DIM + w0);
        } else {
            v = make_float4(0.f, 0.f, 0.f, 0.f);
        }
    };

    // Preload rows h0-2 .. h0+1 into window slots 0..3
    loadRow(h0 - 2, win[0]);
    loadRow(h0 - 1, win[1]);
    loadRow(h0 + 0, win[2]);
    loadRow(h0 + 1, win[3]);

    #pragma unroll
    for (int i = 0; i < R_ROWS; ++i) {
        // bring in row h0+i+2 (the "+2" tap for output row h0+i)
        loadRow(h0 + i + 2, win[(i + 4) % 5]);

        const float4 m2 = win[(i + 0) % 5];
        const float4 m1 = win[(i + 1) % 5];
        const float4 c  = win[(i + 2) % 5];
        const float4 p1 = win[(i + 3) % 5];
        const float4 p2 = win[(i + 4) % 5];

        // horizontal neighbors from adjacent lanes
        float wl2 = __shfl_up(c.z, 1);    // row[w0-2]
        float wl1 = __shfl_up(c.w, 1);    // row[w0-1]
        float wr4 = __shfl_down(c.x, 1);  // row[w0+4]
        float wr5 = __shfl_down(c.y, 1);  // row[w0+5]
        if (lane == 0) {
            const float* row = xp + (size_t)(h0 + i) * W_DIM;
            wl2 = (w0 >= 2) ? row[w0 - 2] : 0.f;
            wl1 = (w0 >= 1) ? row[w0 - 1] : 0.f;
        }
        if (lane == 63) {
            const float* row = xp + (size_t)(h0 + i) * W_DIM;
            wr4 = (w0 + 4 < W_DIM) ? row[w0 + 4] : 0.f;
            wr5 = (w0 + 5 < W_DIM) ? row[w0 + 5] : 0.f;
        }

        float4 xv;
        xv.x = -10.f * m2.x - m1.x + p1.x + 10.f * p2.x;
        xv.y = -10.f * m2.y - m1.y + p1.y + 10.f * p2.y;
        xv.z = -10.f * m2.z - m1.z + p1.z + 10.f * p2.z;
        xv.w = -10.f * m2.w - m1.w + p1.w + 10.f * p2.w;

        float4 xh;
        xh.x = -10.f * wl2 - wl1 + c.y + 10.f * c.z;
        xh.y = -10.f * wl1 - c.x + c.z + 10.f * c.w;
        xh.z = -10.f * c.x - c.y + c.w + 10.f * wr4;
        xh.w = -10.f * c.y - c.z + wr4 + 10.f * wr5;

        vfloat4 o;
        o.x = sqrtf(xv.x * xv.x + xh.x * xh.x + EPS);
        o.y = sqrtf(xv.y * xv.y + xh.y * xh.y + EPS);
        o.z = sqrtf(xv.z * xv.z + xh.z * xh.z + EPS);
        o.w = sqrtf(xv.w * xv.w + xh.w * xh.w + EPS);

        // nontemporal: output is write-once
        __builtin_nontemporal_store(
            o, reinterpret_cast<vfloat4*>(op + (size_t)(h0 + i) * W_DIM + w0));
    }
}

extern "C" void kernel_launch(void* const* d_in, const int* in_sizes, int n_in,
                              void* d_out, int out_size, void* d_ws, size_t ws_size,
                              hipStream_t stream) {
    const float* x   = (const float*)d_in[0];
    float*       out = (float*)d_out;
    const int planes = in_sizes[0] / (H_DIM * W_DIM);  // 16*2 = 32
    const int nwg = planes * (H_DIM / R_ROWS);         // 32 * 32 = 1024

    dim3 block(256, 1, 1);
    dim3 grid(nwg, 1, 1);
    grad_mag_kernel<<<grid, block, 0, stream>>>(x, out);
}